// Round 10
// baseline (405.111 us; speedup 1.0000x reference)
//
#include <hip/hip_runtime.h>
#include <hip/hip_cooperative_groups.h>

#define NGUESS 256
#define CPG 20      // chunks per group
#define NGROUP 50   // 1000 chunks / CPG

// AES inverse S-box: INV_SBOX[SBOX[x]] == x
__device__ __constant__ int INV_SBOXD[256] = {
   82,   9, 106, 213,  48,  54, 165,  56, 191,  64, 163, 158, 129, 243, 215, 251,
  124, 227,  57, 130, 155,  47, 255, 135,  52, 142,  67,  68, 196, 222, 233, 203,
   84, 123, 148,  50, 166, 194,  35,  61, 238,  76, 149,  11,  66, 250, 195,  78,
    8,  46, 161, 102,  40, 217,  36, 178, 118,  91, 162,  73, 109, 139, 209,  37,
  114, 248, 246, 100, 134, 104, 152,  22, 212, 164,  92, 204,  93, 101, 182, 146,
  108, 112,  72,  80, 253, 237, 185, 218,  94,  21,  70,  87, 167, 141, 157, 132,
  144, 216, 171,   0, 140, 188, 211,  10, 247, 228,  88,   5, 184, 179,  69,   6,
  208,  44,  30, 143, 202,  63,  15,   2, 193, 175, 189,   3,   1,  19, 138, 107,
   58, 145,  17,  65,  79, 103, 220, 234, 151, 242, 207, 206, 240, 180, 230, 115,
  150, 172, 116,  34, 231, 173,  53, 133, 226, 249,  55, 232,  28, 117, 223, 110,
   71, 241,  26, 113,  29,  41, 197, 137, 111, 183,  98,  14, 170,  24, 190,  27,
  252,  86,  62,  75, 198, 210, 121,  32, 154, 219, 192, 254, 120, 205,  90, 244,
   31, 221, 168,  51, 136,   7, 199,  49, 177,  18,  16,  89,  39, 128, 236,  95,
   96,  81, 127, 169,  25, 181,  74,  13,  45, 229, 122, 159, 147, 201, 156, 239,
  160, 224,  59,  77, 174,  42, 245, 176, 200, 235, 187,  60, 131,  83, 153,  97,
   23,  43,   4, 126, 186, 119, 214,  38, 225, 105,  20,  99,  85,  33,  12, 125
};

// ONE cooperative kernel, 1000 blocks x 256 threads, 2 grid syncs.
// Phase 1 (per block = one 100x256 chunk): r8's proven paired-chain
// scatter/gather chunk-sum loop -> cs[chunk][g].   (K1 measured at the
// 16us HBM floor in r9; unchanged.)
// Phase 2a (blocks 0..49): 20-chunk group sums -> gsum (double).
// Phase 2b (all blocks): cumsum prefix from gsum + partial chunk rows,
// rank via ballot -> out.
// Co-residency: 20KB LDS -> 8 blocks/CU LDS-wise; __launch_bounds__(256,4)
// caps VGPR<=128 -> >=4 blocks/CU -> capacity 1024 >= 1000 blocks.
__global__ __launch_bounds__(256, 4) void k_fused(const float* __restrict__ pred,
                                                  const int* __restrict__ meta,
                                                  const int* __restrict__ ckp,
                                                  float* __restrict__ cs,
                                                  double* __restrict__ gsum,
                                                  int* __restrict__ outRanks,
                                                  int* __restrict__ outX) {
  __shared__ float prow[4][4][NGUESS];  // [wave][slot][256] 16 KB
  __shared__ float red[4][NGUESS];      // 4 KB

  const int tid = threadIdx.x;
  const int w = tid >> 6;
  const int l = tid & 63;
  const int chunk = blockIdx.x;
  const size_t base = (size_t)chunk * 100 + (size_t)w * 25;

  // ---------------- phase 1: chunk sums ----------------
  {
    const int c0 = l << 2;
    const int t0 = INV_SBOXD[c0 + 0];
    const int t1 = INV_SBOXD[c0 + 1];
    const int t2 = INV_SBOXD[c0 + 2];
    const int t3 = INV_SBOXD[c0 + 3];

    const float* rp = pred + (base << 8) + c0;

    auto scat = [&](float* s, const float4& v) {
      s[t0] = __logf(v.x);
      s[t1] = __logf(v.y);
      s[t2] = __logf(v.z);
      s[t3] = __logf(v.w);
    };

    float s0 = 0.f, s1 = 0.f, s2 = 0.f, s3 = 0.f;
    auto gath = [&](const float* ps, int m) {
      const int mx = m ^ l;
      s0 += ps[mx];
      s1 += ps[mx ^ 64];
      s2 += ps[mx ^ 128];
      s3 += ps[mx ^ 192];
    };

    // prime: pairs 0 (rows 0,1) and 1 (rows 2,3)
    float4 vA = *reinterpret_cast<const float4*>(rp + 0 * NGUESS);
    float4 vB = *reinterpret_cast<const float4*>(rp + 1 * NGUESS);
    float4 nA = *reinterpret_cast<const float4*>(rp + 2 * NGUESS);
    float4 nB = *reinterpret_cast<const float4*>(rp + 3 * NGUESS);
    int pmA = meta[base + 0];
    int pmB = meta[base + 1];

    scat(prow[w][0], vA);
    scat(prow[w][1], vB);

#pragma unroll
    for (int p = 1; p < 12; ++p) {
      vA = nA; vB = nB;
      const int rA = (2 * p + 2 <= 24) ? (2 * p + 2) : 24;
      const int rB = (2 * p + 3 <= 24) ? (2 * p + 3) : 24;
      nA = *reinterpret_cast<const float4*>(rp + (size_t)rA * NGUESS);
      nB = *reinterpret_cast<const float4*>(rp + (size_t)rB * NGUESS);
      const int mA = meta[base + 2 * p];
      const int mB = meta[base + 2 * p + 1];

      float* sA = prow[w][2 * (p & 1)];
      scat(sA, vA);
      scat(sA + NGUESS, vB);

      const float* gA = prow[w][2 * ((p & 1) ^ 1)];
      gath(gA, pmA);
      gath(gA + NGUESS, pmB);

      pmA = mA; pmB = mB;
    }
    // tail: row 24 in nA -> slot 0; gather pair 11 from slots 2,3; then row 24
    scat(prow[w][0], nA);
    gath(prow[w][2], pmA);
    gath(prow[w][3], pmB);
    gath(prow[w][0], meta[base + 24]);

    red[w][l]       = s0;
    red[w][l + 64]  = s1;
    red[w][l + 128] = s2;
    red[w][l + 192] = s3;
    __syncthreads();
    cs[(size_t)chunk * NGUESS + tid] =
        red[0][tid] + red[1][tid] + red[2][tid] + red[3][tid];
  }

  __threadfence();                       // device-scope: cs visible cross-XCD
  cooperative_groups::this_grid().sync();

  // ---------------- phase 2a: group sums (blocks 0..49) ----------------
  if (blockIdx.x < NGROUP) {
    const int b = blockIdx.x, g = tid;
    double s0 = 0.0, s1 = 0.0;
#pragma unroll
    for (int c = 0; c < CPG; c += 2) {
      s0 += (double)cs[(size_t)(b * CPG + c) * NGUESS + g];
      s1 += (double)cs[(size_t)(b * CPG + c + 1) * NGUESS + g];
    }
    gsum[(size_t)b * NGUESS + g] = s0 + s1;
  }

  __threadfence();                       // gsum visible cross-XCD
  cooperative_groups::this_grid().sync();

  // ---------------- phase 2b: rank for this chunk ----------------
  {
    const int c = chunk;
    const int g = tid;
    const int grp = c / CPG;
    const int rem = c - grp * CPG;
    double acc = 0.0, acc2 = 0.0;
#pragma unroll
    for (int bb = 0; bb < NGROUP; bb += 2) {
      if (bb     < grp) acc  += gsum[(size_t)bb       * NGUESS + g];
      if (bb + 1 < grp) acc2 += gsum[(size_t)(bb + 1) * NGUESS + g];
    }
#pragma unroll
    for (int t = 0; t < CPG; t += 2) {
      if (t     <= rem) acc  += (double)cs[(size_t)(grp * CPG + t)     * NGUESS + g];
      if (t + 1 <= rem) acc2 += (double)cs[(size_t)(grp * CPG + t + 1) * NGUESS + g];
    }
    acc += acc2;

    __shared__ double keysh;
    __shared__ int cnt;
    const int ck = *ckp;
    if (g == ck) keysh = acc;
    if (g == 0) cnt = 0;
    __syncthreads();
    const unsigned long long mball = __ballot(acc > keysh);
    if ((g & 63) == 0) atomicAdd(&cnt, (int)__popcll(mball));
    __syncthreads();
    if (g == 0) {
      outRanks[c] = cnt;
      outX[c] = (c + 1) * 100;
    }
  }
}

extern "C" void kernel_launch(void* const* d_in, const int* in_sizes, int n_in,
                              void* d_out, int out_size, void* d_ws, size_t ws_size,
                              hipStream_t stream) {
  const float* pred = (const float*)d_in[0];
  const int* meta   = (const int*)d_in[1];
  // d_in[2] = guess_range (256), d_in[3] = correct_key (34), d_in[4] = step (100)
  const int* ckp    = (const int*)d_in[3];

  const int N = in_sizes[1];             // 100000
  const int num_chunks = N / 100;        // 1000

  float*  cs   = (float*)d_ws;                                            // [1000][256] f32
  double* gsum = (double*)((char*)d_ws +
                           (size_t)num_chunks * NGUESS * sizeof(float));  // [50][256] f64

  int* outRanks = (int*)d_out;           // ranks[0..nc)
  int* outX     = outRanks + num_chunks; // x_rank[nc..2nc)

  void* args[] = {(void*)&pred, (void*)&meta, (void*)&ckp, (void*)&cs,
                  (void*)&gsum, (void*)&outRanks, (void*)&outX};
  hipLaunchCooperativeKernel((const void*)k_fused, dim3(num_chunks), dim3(256),
                             args, 0, stream);
}

// Round 11
// 83.269 us; speedup vs baseline: 4.8651x; 4.8651x over previous
//
#include <hip/hip_runtime.h>

#define NGUESS 256
#define CPG 20      // chunks per group
#define NGROUP 50   // 1000 chunks / CPG

// AES inverse S-box: INV_SBOX[SBOX[x]] == x
__device__ __constant__ int INV_SBOXD[256] = {
   82,   9, 106, 213,  48,  54, 165,  56, 191,  64, 163, 158, 129, 243, 215, 251,
  124, 227,  57, 130, 155,  47, 255, 135,  52, 142,  67,  68, 196, 222, 233, 203,
   84, 123, 148,  50, 166, 194,  35,  61, 238,  76, 149,  11,  66, 250, 195,  78,
    8,  46, 161, 102,  40, 217,  36, 178, 118,  91, 162,  73, 109, 139, 209,  37,
  114, 248, 246, 100, 134, 104, 152,  22, 212, 164,  92, 204,  93, 101, 182, 146,
  108, 112,  72,  80, 253, 237, 185, 218,  94,  21,  70,  87, 167, 141, 157, 132,
  144, 216, 171,   0, 140, 188, 211,  10, 247, 228,  88,   5, 184, 179,  69,   6,
  208,  44,  30, 143, 202,  63,  15,   2, 193, 175, 189,   3,   1,  19, 138, 107,
   58, 145,  17,  65,  79, 103, 220, 234, 151, 242, 207, 206, 240, 180, 230, 115,
  150, 172, 116,  34, 231, 173,  53, 133, 226, 249,  55, 232,  28, 117, 223, 110,
   71, 241,  26, 113,  29,  41, 197, 137, 111, 183,  98,  14, 170,  24, 190,  27,
  252,  86,  62,  75, 198, 210, 121,  32, 154, 219, 192, 254, 120, 205,  90, 244,
   31, 221, 168,  51, 136,   7, 199,  49, 177,  18,  16,  89,  39, 128, 236,  95,
   96,  81, 127, 169,  25, 181,  74,  13,  45, 229, 122, 159, 147, 201, 156, 239,
  160, 224,  59,  77, 174,  42, 245, 176, 200, 235, 187,  60, 131,  83, 153,  97,
   23,  43,   4, 126, 186, 119, 214,  38, 225, 105,  20,  99,  85,  33,  12, 125
};

// K1: r8's proven kernel, unchanged (r9 measured it at ~16us = HBM floor).
// One block per 100x256 chunk; wave w owns rows [25w,25w+25); paired-chain
// scatter(log at inv_sbox) / gather(m^l XOR-indexed, conflict-free).
__global__ __launch_bounds__(256) void k_chunksums(const float* __restrict__ pred,
                                                   const int* __restrict__ meta,
                                                   float* __restrict__ cs) {
  __shared__ float prow[4][4][NGUESS];  // [wave][slot][256] 16 KB
  __shared__ float red[4][NGUESS];      // 4 KB

  const int tid = threadIdx.x;
  const int w = tid >> 6;
  const int l = tid & 63;
  const size_t base = (size_t)blockIdx.x * 100 + (size_t)w * 25;

  const int c0 = l << 2;
  const int t0 = INV_SBOXD[c0 + 0];
  const int t1 = INV_SBOXD[c0 + 1];
  const int t2 = INV_SBOXD[c0 + 2];
  const int t3 = INV_SBOXD[c0 + 3];

  const float* rp = pred + (base << 8) + c0;

  auto scat = [&](float* s, const float4& v) {
    s[t0] = __logf(v.x);
    s[t1] = __logf(v.y);
    s[t2] = __logf(v.z);
    s[t3] = __logf(v.w);
  };

  float s0 = 0.f, s1 = 0.f, s2 = 0.f, s3 = 0.f;
  auto gath = [&](const float* ps, int m) {
    const int mx = m ^ l;
    s0 += ps[mx];
    s1 += ps[mx ^ 64];
    s2 += ps[mx ^ 128];
    s3 += ps[mx ^ 192];
  };

  float4 vA = *reinterpret_cast<const float4*>(rp + 0 * NGUESS);
  float4 vB = *reinterpret_cast<const float4*>(rp + 1 * NGUESS);
  float4 nA = *reinterpret_cast<const float4*>(rp + 2 * NGUESS);
  float4 nB = *reinterpret_cast<const float4*>(rp + 3 * NGUESS);
  int pmA = meta[base + 0];
  int pmB = meta[base + 1];

  scat(prow[w][0], vA);
  scat(prow[w][1], vB);

#pragma unroll
  for (int p = 1; p < 12; ++p) {
    vA = nA; vB = nB;
    const int rA = (2 * p + 2 <= 24) ? (2 * p + 2) : 24;
    const int rB = (2 * p + 3 <= 24) ? (2 * p + 3) : 24;
    nA = *reinterpret_cast<const float4*>(rp + (size_t)rA * NGUESS);
    nB = *reinterpret_cast<const float4*>(rp + (size_t)rB * NGUESS);
    const int mA = meta[base + 2 * p];
    const int mB = meta[base + 2 * p + 1];

    float* sA = prow[w][2 * (p & 1)];
    scat(sA, vA);
    scat(sA + NGUESS, vB);

    const float* gA = prow[w][2 * ((p & 1) ^ 1)];
    gath(gA, pmA);
    gath(gA + NGUESS, pmB);

    pmA = mA; pmB = mB;
  }

  scat(prow[w][0], nA);
  gath(prow[w][2], pmA);
  gath(prow[w][3], pmB);
  gath(prow[w][0], meta[base + 24]);

  red[w][l]       = s0;
  red[w][l + 64]  = s1;
  red[w][l + 128] = s2;
  red[w][l + 192] = s3;
  __syncthreads();
  cs[((size_t)blockIdx.x) * NGUESS + tid] =
      red[0][tid] + red[1][tid] + red[2][tid] + red[3][tid];
}

// K2 (single dispatch, replaces K2a+K2b): one block per GROUP of 20 chunks.
// Thread g owns column g. Phase A: direct double prefix over all previous
// groups' chunk rows (worst block reads 980 rows = 1MB from L2/L3; replaces
// a whole gsum dispatch + boundary). Phase B: 20 running scores kept in
// registers (fully unrolled -> no scratch), key column via LDS, 20 ballots.
__global__ __launch_bounds__(256) void k_ranks2(const float* __restrict__ cs,
                                                const int* __restrict__ ckp,
                                                int* __restrict__ outRanks,
                                                int* __restrict__ outX) {
  const int b = blockIdx.x;       // group id
  const int g = threadIdx.x;      // column / guess
  const int nprev = b * CPG;      // rows before this group (multiple of 4)

  double acc = 0.0, acc2 = 0.0;
  for (int cc = 0; cc < nprev; cc += 4) {   // 4 independent loads/iter
    acc  += (double)cs[(size_t)(cc + 0) * NGUESS + g];
    acc2 += (double)cs[(size_t)(cc + 1) * NGUESS + g];
    acc  += (double)cs[(size_t)(cc + 2) * NGUESS + g];
    acc2 += (double)cs[(size_t)(cc + 3) * NGUESS + g];
  }
  acc += acc2;

  // this group's 20 chunks: running prefix, all in registers (static idx)
  double accs[CPG];
#pragma unroll
  for (int t = 0; t < CPG; ++t) {
    acc += (double)cs[(size_t)(nprev + t) * NGUESS + g];
    accs[t] = acc;
  }

  __shared__ double keys[CPG];
  __shared__ int cnts[CPG];
  const int ck = *ckp;
  if (g == ck) {
#pragma unroll
    for (int t = 0; t < CPG; ++t) keys[t] = accs[t];
  }
  if (g < CPG) cnts[g] = 0;
  __syncthreads();
#pragma unroll
  for (int t = 0; t < CPG; ++t) {
    const unsigned long long mb = __ballot(accs[t] > keys[t]);
    if ((g & 63) == 0) atomicAdd(&cnts[t], (int)__popcll(mb));
  }
  __syncthreads();
  if (g < CPG) {
    const int c = b * CPG + g;
    outRanks[c] = cnts[g];
    outX[c] = (c + 1) * 100;
  }
}

extern "C" void kernel_launch(void* const* d_in, const int* in_sizes, int n_in,
                              void* d_out, int out_size, void* d_ws, size_t ws_size,
                              hipStream_t stream) {
  const float* pred = (const float*)d_in[0];
  const int* meta   = (const int*)d_in[1];
  // d_in[2] = guess_range (256), d_in[3] = correct_key (34), d_in[4] = step (100)
  const int* ckp    = (const int*)d_in[3];

  const int N = in_sizes[1];             // 100000
  const int num_chunks = N / 100;        // 1000

  float* cs = (float*)d_ws;              // [1000][256] f32

  int* outRanks = (int*)d_out;           // ranks[0..nc)
  int* outX     = outRanks + num_chunks; // x_rank[nc..2nc)

  k_chunksums<<<num_chunks, 256, 0, stream>>>(pred, meta, cs);
  k_ranks2   <<<NGROUP,     256, 0, stream>>>(cs, ckp, outRanks, outX);
}

// Round 12
// 31.420 us; speedup vs baseline: 12.8936x; 2.6502x over previous
//
#include <hip/hip_runtime.h>

#define NGUESS 256
#define NCHUNK 1000

// AES inverse S-box: INV_SBOX[SBOX[x]] == x
__device__ __constant__ int INV_SBOXD[256] = {
   82,   9, 106, 213,  48,  54, 165,  56, 191,  64, 163, 158, 129, 243, 215, 251,
  124, 227,  57, 130, 155,  47, 255, 135,  52, 142,  67,  68, 196, 222, 233, 203,
   84, 123, 148,  50, 166, 194,  35,  61, 238,  76, 149,  11,  66, 250, 195,  78,
    8,  46, 161, 102,  40, 217,  36, 178, 118,  91, 162,  73, 109, 139, 209,  37,
  114, 248, 246, 100, 134, 104, 152,  22, 212, 164,  92, 204,  93, 101, 182, 146,
  108, 112,  72,  80, 253, 237, 185, 218,  94,  21,  70,  87, 167, 141, 157, 132,
  144, 216, 171,   0, 140, 188, 211,  10, 247, 228,  88,   5, 184, 179,  69,   6,
  208,  44,  30, 143, 202,  63,  15,   2, 193, 175, 189,   3,   1,  19, 138, 107,
   58, 145,  17,  65,  79, 103, 220, 234, 151, 242, 207, 206, 240, 180, 230, 115,
  150, 172, 116,  34, 231, 173,  53, 133, 226, 249,  55, 232,  28, 117, 223, 110,
   71, 241,  26, 113,  29,  41, 197, 137, 111, 183,  98,  14, 170,  24, 190,  27,
  252,  86,  62,  75, 198, 210, 121,  32, 154, 219, 192, 254, 120, 205,  90, 244,
   31, 221, 168,  51, 136,   7, 199,  49, 177,  18,  16,  89,  39, 128, 236,  95,
   96,  81, 127, 169,  25, 181,  74,  13,  45, 229, 122, 159, 147, 201, 156, 239,
  160, 224,  59,  77, 174,  42, 245, 176, 200, 235, 187,  60, 131,  83, 153,  97,
   23,  43,   4, 126, 186, 119, 214,  38, 225, 105,  20,  99,  85,  33,  12, 125
};

// K1: r8's proven kernel, unchanged (r9 measured it at ~16us = HBM floor).
// One block per 100x256 chunk; wave w owns rows [25w,25w+25); paired-chain
// scatter(log at inv_sbox) / gather(m^l XOR-indexed, conflict-free).
__global__ __launch_bounds__(256) void k_chunksums(const float* __restrict__ pred,
                                                   const int* __restrict__ meta,
                                                   float* __restrict__ cs) {
  __shared__ float prow[4][4][NGUESS];  // [wave][slot][256] 16 KB
  __shared__ float red[4][NGUESS];      // 4 KB

  const int tid = threadIdx.x;
  const int w = tid >> 6;
  const int l = tid & 63;
  const size_t base = (size_t)blockIdx.x * 100 + (size_t)w * 25;

  const int c0 = l << 2;
  const int t0 = INV_SBOXD[c0 + 0];
  const int t1 = INV_SBOXD[c0 + 1];
  const int t2 = INV_SBOXD[c0 + 2];
  const int t3 = INV_SBOXD[c0 + 3];

  const float* rp = pred + (base << 8) + c0;

  auto scat = [&](float* s, const float4& v) {
    s[t0] = __logf(v.x);
    s[t1] = __logf(v.y);
    s[t2] = __logf(v.z);
    s[t3] = __logf(v.w);
  };

  float s0 = 0.f, s1 = 0.f, s2 = 0.f, s3 = 0.f;
  auto gath = [&](const float* ps, int m) {
    const int mx = m ^ l;
    s0 += ps[mx];
    s1 += ps[mx ^ 64];
    s2 += ps[mx ^ 128];
    s3 += ps[mx ^ 192];
  };

  float4 vA = *reinterpret_cast<const float4*>(rp + 0 * NGUESS);
  float4 vB = *reinterpret_cast<const float4*>(rp + 1 * NGUESS);
  float4 nA = *reinterpret_cast<const float4*>(rp + 2 * NGUESS);
  float4 nB = *reinterpret_cast<const float4*>(rp + 3 * NGUESS);
  int pmA = meta[base + 0];
  int pmB = meta[base + 1];

  scat(prow[w][0], vA);
  scat(prow[w][1], vB);

#pragma unroll
  for (int p = 1; p < 12; ++p) {
    vA = nA; vB = nB;
    const int rA = (2 * p + 2 <= 24) ? (2 * p + 2) : 24;
    const int rB = (2 * p + 3 <= 24) ? (2 * p + 3) : 24;
    nA = *reinterpret_cast<const float4*>(rp + (size_t)rA * NGUESS);
    nB = *reinterpret_cast<const float4*>(rp + (size_t)rB * NGUESS);
    const int mA = meta[base + 2 * p];
    const int mB = meta[base + 2 * p + 1];

    float* sA = prow[w][2 * (p & 1)];
    scat(sA, vA);
    scat(sA + NGUESS, vB);

    const float* gA = prow[w][2 * ((p & 1) ^ 1)];
    gath(gA, pmA);
    gath(gA + NGUESS, pmB);

    pmA = mA; pmB = mB;
  }

  scat(prow[w][0], nA);
  gath(prow[w][2], pmA);
  gath(prow[w][3], pmB);
  gath(prow[w][0], meta[base + 24]);

  red[w][l]       = s0;
  red[w][l + 64]  = s1;
  red[w][l + 128] = s2;
  red[w][l + 192] = s3;
  __syncthreads();
  cs[((size_t)blockIdx.x) * NGUESS + tid] =
      red[0][tid] + red[1][tid] + red[2][tid] + red[3][tid];
}

// K2a': block-scan per COLUMN. 256 blocks (one per guess g); thread t owns
// chunks [4t, 4t+4): 4 independent loads, 3-add local prefix, 8-step
// Hillis-Steele LDS scan of the 256 thread-totals, write 4 inclusive
// prefixes (double). Replaces gsum dispatch + K2b's 45-load prefix rebuild.
__global__ __launch_bounds__(256) void k_scan(const float* __restrict__ cs,
                                              double* __restrict__ S,
                                              int nc) {
  const int g = blockIdx.x;
  const int t = threadIdx.x;
  const int r0 = t << 2;

  const double x0 = (r0 + 0 < nc) ? (double)cs[(size_t)(r0 + 0) * NGUESS + g] : 0.0;
  const double x1 = (r0 + 1 < nc) ? (double)cs[(size_t)(r0 + 1) * NGUESS + g] : 0.0;
  const double x2 = (r0 + 2 < nc) ? (double)cs[(size_t)(r0 + 2) * NGUESS + g] : 0.0;
  const double x3 = (r0 + 3 < nc) ? (double)cs[(size_t)(r0 + 3) * NGUESS + g] : 0.0;
  const double p0 = x0;
  const double p1 = p0 + x1;
  const double p2 = p1 + x2;
  const double p3 = p2 + x3;

  __shared__ double sc[256];
  sc[t] = p3;
  __syncthreads();
#pragma unroll
  for (int off = 1; off < 256; off <<= 1) {
    const double v = sc[t];
    const double u = (t >= off) ? sc[t - off] : 0.0;
    __syncthreads();
    sc[t] = v + u;
    __syncthreads();
  }
  const double E = (t > 0) ? sc[t - 1] : 0.0;  // exclusive prefix of this thread

  if (r0 + 0 < nc) S[(size_t)(r0 + 0) * NGUESS + g] = E + p0;
  if (r0 + 1 < nc) S[(size_t)(r0 + 1) * NGUESS + g] = E + p1;
  if (r0 + 2 < nc) S[(size_t)(r0 + 2) * NGUESS + g] = E + p2;
  if (r0 + 3 < nc) S[(size_t)(r0 + 3) * NGUESS + g] = E + p3;
}

// K2b': one block per chunk; ONE coalesced load + ballot + popcount.
__global__ __launch_bounds__(256) void k_ranks3(const double* __restrict__ S,
                                                const int* __restrict__ ckp,
                                                int* __restrict__ outRanks,
                                                int* __restrict__ outX) {
  const int c = blockIdx.x;
  const int g = threadIdx.x;
  const double s = S[(size_t)c * NGUESS + g];

  __shared__ double keysh;
  __shared__ int cnt;
  if (g == *ckp) keysh = s;
  if (g == 0) cnt = 0;
  __syncthreads();
  const unsigned long long mb = __ballot(s > keysh);
  if ((g & 63) == 0) atomicAdd(&cnt, (int)__popcll(mb));
  __syncthreads();
  if (g == 0) {
    outRanks[c] = cnt;
    outX[c] = (c + 1) * 100;
  }
}

extern "C" void kernel_launch(void* const* d_in, const int* in_sizes, int n_in,
                              void* d_out, int out_size, void* d_ws, size_t ws_size,
                              hipStream_t stream) {
  const float* pred = (const float*)d_in[0];
  const int* meta   = (const int*)d_in[1];
  // d_in[2] = guess_range (256), d_in[3] = correct_key (34), d_in[4] = step (100)
  const int* ckp    = (const int*)d_in[3];

  const int N = in_sizes[1];             // 100000
  const int num_chunks = N / 100;        // 1000

  double* S  = (double*)d_ws;                                   // [1000][256] f64 (8B-aligned at base)
  float*  cs = (float*)((char*)d_ws +
                        (size_t)num_chunks * NGUESS * sizeof(double)); // [1000][256] f32

  int* outRanks = (int*)d_out;           // ranks[0..nc)
  int* outX     = outRanks + num_chunks; // x_rank[nc..2nc)

  k_chunksums<<<num_chunks, 256, 0, stream>>>(pred, meta, cs);
  k_scan     <<<NGUESS,     256, 0, stream>>>(cs, S, num_chunks);
  k_ranks3   <<<num_chunks, 256, 0, stream>>>(S, ckp, outRanks, outX);
}